// Round 1
// baseline (204.738 us; speedup 1.0000x reference)
//
#include <hip/hip_runtime.h>

#define S 512
#define SP 520        // padded compact diag row (8 trailing zeros)
#define UNITS 9
#define BCHUNK 10     // batches per main block

// ---------------- workspace layout ----------------
// [0x00000 ) diag     : B*SP floats   (208 KB)
// [0x40000 ) bias_sum : S*S floats    (1.05 MB)
#define BIAS_OFF (0x40000)
#define WS_NEED  (BIAS_OFF + S * S * 4)

// One block per i-row: sum bias row, and (grid-stride) extract diag.
// No w transpose anymore: main reads w directly in its native layout.
__global__ __launch_bounds__(256) void prep_kernel(
        const float* __restrict__ bv, const float* __restrict__ in,
        float* __restrict__ diag, float* __restrict__ bias_sum, int B) {
    __shared__ __align__(16) float sb[S * UNITS];   // 18 KB

    const int i   = blockIdx.x;
    const int tid = threadIdx.x;

    // diag extraction, spread across the whole grid (512*256 threads > 100*520)
    {
        int idx = blockIdx.x * 256 + tid;
        if (idx < B * SP) {
            int b = idx / SP;
            int j = idx - b * SP;
            diag[idx] = (j < S) ? in[(size_t)b * S * S + (size_t)j * (S + 1)] : 0.f;
        }
    }

    // stage b row into LDS, fully coalesced float4
    {
        const float4* br = reinterpret_cast<const float4*>(bv + (size_t)i * S * UNITS);
        float4* sb4 = reinterpret_cast<float4*>(sb);
        for (int q = tid; q < S * UNITS / 4; q += 256)   // 1152 float4
            sb4[q] = br[q];
    }
    __syncthreads();

    for (int j = tid; j < S; j += 256) {
        float s = 0.f;
        #pragma unroll
        for (int t = 0; t < UNITS; ++t) s += sb[j * UNITS + t];   // stride-9: conflict-free
        bias_sum[(size_t)i * S + j] = s;
    }
}

// 2 i-rows per block, 128 threads per row, each thread owns one float4 of output.
// Weights read directly from w (36 contiguous floats per thread, 16B-aligned).
__global__ __launch_bounds__(256) void cnn_main_kernel(
        const float* __restrict__ w, const float* __restrict__ bias_sum,
        const float* __restrict__ diag, float* __restrict__ out, int B) {
    const int group = blockIdx.x & ((S / 2) - 1);   // 0..255 -> i pair
    const int chunk = blockIdx.x >> 8;              // batch chunk
    const int r     = threadIdx.x >> 7;             // 0..1
    const int jl    = threadIdx.x & 127;
    const int i     = group * 2 + r;
    const int j0    = jl * 4;

    // ---- registers: 9 float4 loads of w (native [i,j,t] layout) ----
    float wv[4 * UNITS];                            // wv[k*UNITS + t] = w[i, j0+k, t]
    {
        const float4* w4 = reinterpret_cast<const float4*>(
            w + (size_t)(i * S + j0) * UNITS);      // (i*512+4*jl)*9 floats -> 16B aligned
        #pragma unroll
        for (int q = 0; q < 9; ++q) {
            float4 v = w4[q];
            wv[4*q+0] = v.x; wv[4*q+1] = v.y; wv[4*q+2] = v.z; wv[4*q+3] = v.w;
        }
    }
    // valid_i mask: only the last two rows (i=510 -> tmax 6, i=511 -> tmax 3)
    if (i >= S - 2) {
        const int tmax = 3 * (S - i);
        #pragma unroll
        for (int k = 0; k < 4; ++k)
            #pragma unroll
            for (int t = 0; t < UNITS; ++t)
                if (t >= tmax) wv[k * UNITS + t] = 0.f;
    }
    const float4 bias = *reinterpret_cast<const float4*>(
        bias_sum + (size_t)i * S + j0);

    const float* bp = &bias.x;

    auto body = [&](int b) {
        // 12 diag values: 3 overlapping-across-lanes but per-inst coalesced float4
        float dv[12];
        {
            const float4* p = reinterpret_cast<const float4*>(diag + (size_t)b * SP + j0);
            #pragma unroll
            for (int q = 0; q < 3; ++q) {
                float4 v = p[q];
                dv[4*q+0] = v.x; dv[4*q+1] = v.y; dv[4*q+2] = v.z; dv[4*q+3] = v.w;
            }
        }
        float4 res;
        float* rp = &res.x;
        #pragma unroll
        for (int k = 0; k < 4; ++k) {
            float acc = 0.f;
            #pragma unroll
            for (int t = 0; t < UNITS; ++t)
                acc = fmaf(dv[k + t], wv[k * UNITS + t], acc);
            rp[k] = fmaf(acc, (float)UNITS, bp[k]);
        }
        // full-line store: wave writes 1024B contiguous
        *reinterpret_cast<float4*>(out + (size_t)b * S * S + (size_t)i * S + j0) = res;
    };

    const int b0 = chunk * BCHUNK;
    const int nb = min(BCHUNK, B - b0);
    if (nb == BCHUNK) {
        // fixed trip count: lets the compiler unroll/pipeline the batch loop
        #pragma unroll 2
        for (int bb = 0; bb < BCHUNK; ++bb) body(b0 + bb);
    } else {
        for (int bb = 0; bb < nb; ++bb) body(b0 + bb);
    }
}

// ---- fallback (ws too small): self-contained, reads raw input via LDS ----
__global__ __launch_bounds__(256) void cnn_fallback_kernel(
        const float* __restrict__ w, const float* __restrict__ bv,
        const float* __restrict__ raw_in, float* __restrict__ out, int B) {
    __shared__ __align__(16) float sdiag[SP];
    const int group = blockIdx.x & ((S / 2) - 1);
    const int chunk = blockIdx.x >> 8;
    const int r     = threadIdx.x >> 7;
    const int jl    = threadIdx.x & 127;
    const int i     = group * 2 + r;
    const int j0    = jl * 4;

    float wv[4 * UNITS];
    {
        const float4* ws4 = reinterpret_cast<const float4*>(w + (size_t)(i * S + j0) * UNITS);
        #pragma unroll
        for (int q = 0; q < 9; ++q) {
            float4 v = ws4[q];
            wv[4*q] = v.x; wv[4*q+1] = v.y; wv[4*q+2] = v.z; wv[4*q+3] = v.w;
        }
    }
    if (i >= S - 2) {
        const int tmax = 3 * (S - i);
        #pragma unroll
        for (int k = 0; k < 4; ++k)
            #pragma unroll
            for (int t = 0; t < UNITS; ++t)
                if (t >= tmax) wv[k * UNITS + t] = 0.f;
    }
    float bias[4];
    {
        float tmp[4 * UNITS];
        const float4* bs4 = reinterpret_cast<const float4*>(bv + (size_t)(i * S + j0) * UNITS);
        #pragma unroll
        for (int q = 0; q < 9; ++q) {
            float4 v = bs4[q];
            tmp[4*q] = v.x; tmp[4*q+1] = v.y; tmp[4*q+2] = v.z; tmp[4*q+3] = v.w;
        }
        #pragma unroll
        for (int k = 0; k < 4; ++k) {
            float s = 0.f;
            #pragma unroll
            for (int t = 0; t < UNITS; ++t) s += tmp[k * UNITS + t];
            bias[k] = s;
        }
    }
    const int b0 = chunk * BCHUNK;
    for (int bb = 0; bb < BCHUNK; ++bb) {
        const int b = b0 + bb;
        if (b >= B) break;
        __syncthreads();
        for (int idx = threadIdx.x; idx < SP; idx += 256)
            sdiag[idx] = (idx < S) ? raw_in[(size_t)b * S * S + (size_t)idx * (S + 1)] : 0.f;
        __syncthreads();
        float dv[12];
        #pragma unroll
        for (int q = 0; q < 3; ++q) {
            float4 v = reinterpret_cast<const float4*>(&sdiag[j0])[q];
            dv[4*q] = v.x; dv[4*q+1] = v.y; dv[4*q+2] = v.z; dv[4*q+3] = v.w;
        }
        float4 res; float* rp = &res.x;
        #pragma unroll
        for (int k = 0; k < 4; ++k) {
            float acc = 0.f;
            #pragma unroll
            for (int t = 0; t < UNITS; ++t)
                acc = fmaf(dv[k + t], wv[k * UNITS + t], acc);
            rp[k] = fmaf(acc, (float)UNITS, bias[k]);
        }
        *reinterpret_cast<float4*>(out + (size_t)b * S * S + (size_t)i * S + j0) = res;
    }
}

extern "C" void kernel_launch(void* const* d_in, const int* in_sizes, int n_in,
                              void* d_out, int out_size, void* d_ws, size_t ws_size,
                              hipStream_t stream) {
    const float* in = (const float*)d_in[0];
    const float* w  = (const float*)d_in[1];
    const float* bv = (const float*)d_in[2];
    float* out      = (float*)d_out;

    const int B = in_sizes[0] / (S * S);           // 100
    const int nchunk = (B + BCHUNK - 1) / BCHUNK;  // 10
    dim3 grid((S / 2) * nchunk);                   // 2560 blocks

    if (ws_size >= (size_t)WS_NEED) {
        char* ws = (char*)d_ws;
        float* diag     = (float*)(ws);
        float* bias_sum = (float*)(ws + BIAS_OFF);
        prep_kernel<<<S, 256, 0, stream>>>(bv, in, diag, bias_sum, B);
        cnn_main_kernel<<<grid, 256, 0, stream>>>(w, bias_sum, diag, out, B);
    } else {
        cnn_fallback_kernel<<<grid, 256, 0, stream>>>(w, bv, in, out, B);
    }
}